// Round 5
// baseline (432.884 us; speedup 1.0000x reference)
//
#include <hip/hip_runtime.h>

// RGAT 2-layer + BN/ELU + head for MI355X (gfx950).
// Float inputs may be bf16 OR fp32 (runtime-detected); ints are int32.
// Internal compute fp32 in workspace. Output stored in detected float width.
//
// CSR build: 512-bucket LDS-staged partition (coalesced run flushes)
// + per-bucket CSR finalize (single-block-local random writes).
// Transforms: one wave per (64-node tile, relation) — wave-uniform relation
// makes all weight loads scalar (s_load); LDS-staged node rows (bf16 path).

typedef unsigned short ushort_t;
typedef unsigned int uint_t;

#define NEG_SLOPE 0.2f
#define BN_EPS 1e-5f
#define CAP 256     // per-node LDS alpha cache in gather (recompute fallback)
#define NBUCK 512   // partition buckets

__device__ __forceinline__ float bf2f(ushort_t u) {
    return __uint_as_float(((uint_t)u) << 16);
}
__device__ __forceinline__ ushort_t f2bf(float f) {
    uint_t x = __float_as_uint(f);
    x += 0x7FFFu + ((x >> 16) & 1u);   // round-to-nearest-even
    return (ushort_t)(x >> 16);
}
// generic float load: bf16 (isb=1) or fp32 (isb=0)
__device__ __forceinline__ float loadf(const void* p, int i, int isb) {
    return isb ? bf2f(((const ushort_t*)p)[i]) : ((const float*)p)[i];
}

// ---------------- input dtype detection ----------------
__global__ void k_detect(const uint_t* __restrict__ x, int* __restrict__ flag) {
    int t = threadIdx.x;
    uint_t u = x[t * 37];
    uint_t lo_exp = (u >> 7) & 0xFF;
    int like = (lo_exp >= 96 && lo_exp <= 150) ? 1 : 0;
    __shared__ int cnt;
    if (t == 0) cnt = 0;
    __syncthreads();
    atomicAdd(&cnt, like);
    __syncthreads();
    if (t == 0) flag[0] = (cnt > 192) ? 1 : 0;
}

// ---------------- bucket histogram ----------------
__global__ __launch_bounds__(256) void k_hist(const int* __restrict__ ei,
                                              int* __restrict__ hist, int E, int npb) {
    __shared__ int h[NBUCK];
    int t = threadIdx.x;
    for (int i = t; i < NBUCK; i += 256) h[i] = 0;
    __syncthreads();
    int e0 = blockIdx.x * 4096;
    for (int i = 0; i < 16; ++i) {
        int e = e0 + i * 256 + t;
        if (e < E) atomicAdd(&h[ei[E + e] / npb], 1);
    }
    __syncthreads();
    for (int i = t; i < NBUCK; i += 256) {
        int c = h[i];
        if (c) atomicAdd(&hist[i], c);
    }
}

// ---------------- bucket base scan ----------------
__global__ __launch_bounds__(NBUCK) void k_bscan(const int* __restrict__ hist,
                                                 int* __restrict__ base,
                                                 int* __restrict__ cursor,
                                                 int* __restrict__ row_ptr,
                                                 int N, int E) {
    __shared__ int sc[NBUCK];
    int t = threadIdx.x;
    int v = hist[t];
    sc[t] = v;
    __syncthreads();
    for (int off = 1; off < NBUCK; off <<= 1) {
        int x = (t >= off) ? sc[t - off] : 0;
        __syncthreads();
        sc[t] += x;
        __syncthreads();
    }
    int ex = sc[t] - v;
    base[t] = ex;
    cursor[t] = ex;
    if (t == NBUCK - 1) { base[NBUCK] = E; row_ptr[N] = E; }
}

// ---------------- LDS-staged bucket partition ----------------
// tmp record: x = src | et<<23 | ldst<<25 ; y = eattr fp32 bits
__global__ __launch_bounds__(512) void k_bucket(const int* __restrict__ ei,
                                                const int* __restrict__ et,
                                                const void* __restrict__ ea,
                                                const int* __restrict__ flag,
                                                int* __restrict__ bcur,
                                                int2* __restrict__ tmp,
                                                int E, int npb) {
    extern __shared__ int2 srec[];           // 8192 records = 64 KB
    __shared__ int cnt[NBUCK];
    __shared__ int lofs[NBUCK + 1];
    __shared__ int gpos[NBUCK];
    int t = threadIdx.x;
    int isb = flag[0];
    cnt[t] = 0;
    __syncthreads();
    int e0 = blockIdx.x * 8192;
    // pass 1: count
    for (int i = 0; i < 16; ++i) {
        int e = e0 + i * 512 + t;
        if (e < E) atomicAdd(&cnt[ei[E + e] / npb], 1);
    }
    __syncthreads();
    int myc = cnt[t];
    // inclusive scan in place
    for (int off = 1; off < NBUCK; off <<= 1) {
        int v = (t >= off) ? cnt[t - off] : 0;
        __syncthreads();
        cnt[t] += v;
        __syncthreads();
    }
    lofs[t] = cnt[t] - myc;
    if (t == NBUCK - 1) lofs[NBUCK] = cnt[NBUCK - 1];
    __syncthreads();
    cnt[t] = lofs[t];   // reuse as local cursor
    __syncthreads();
    // pass 2: place into LDS grouped by bucket
    for (int i = 0; i < 16; ++i) {
        int e = e0 + i * 512 + t;
        if (e < E) {
            int d = ei[E + e];
            int b = d / npb;
            int ldst = d - b * npb;
            int idx = atomicAdd(&cnt[b], 1);
            int2 r;
            r.x = (int)((uint_t)ei[e] | ((uint_t)et[e] << 23) | ((uint_t)ldst << 25));
            r.y = __float_as_int(loadf(ea, e, isb));
            srec[idx] = r;
        }
    }
    __syncthreads();
    // reserve global ranges (one atomic per bucket per block)
    int c_b = lofs[t + 1] - lofs[t];
    gpos[t] = atomicAdd(&bcur[t], c_b);
    __syncthreads();
    // flush: contiguous runs per bucket (binary search slot -> bucket)
    int total = lofs[NBUCK];
    for (int i = t; i < total; i += 512) {
        int lo = 0, hi = NBUCK - 1;
        while (lo < hi) {
            int mid = (lo + hi + 1) >> 1;
            if (lofs[mid] <= i) lo = mid; else hi = mid - 1;
        }
        tmp[gpos[lo] + (i - lofs[lo])] = srec[i];
    }
}

// ---------------- per-bucket CSR finalize ----------------
__global__ __launch_bounds__(256) void k_b2csr(const int2* __restrict__ tmp,
                                               const int* __restrict__ base,
                                               int* __restrict__ row_ptr,
                                               int2* __restrict__ ebuf,
                                               int N, int npb) {
    __shared__ int cnt[128];
    __shared__ int lofs[129];
    int b = blockIdx.x, t = threadIdx.x;
    int s0 = base[b], s1 = base[b + 1];
    if (t < 128) cnt[t] = 0;
    __syncthreads();
    for (int p = s0 + t; p < s1; p += 256) {
        uint_t x = (uint_t)tmp[p].x;
        atomicAdd(&cnt[(x >> 25) & 0x7F], 1);
    }
    __syncthreads();
    int myc = (t < 128) ? cnt[t] : 0;
    for (int off = 1; off < 128; off <<= 1) {
        int v = (t >= off && t < 128) ? cnt[t - off] : 0;
        __syncthreads();
        if (t < 128) cnt[t] += v;
        __syncthreads();
    }
    if (t < 128) {
        lofs[t] = cnt[t] - myc;
        if (t == 127) lofs[128] = cnt[127];
    }
    __syncthreads();
    int node0 = b * npb;
    if (t < npb && node0 + t < N) row_ptr[node0 + t] = s0 + lofs[t];
    if (t < 128) cnt[t] = lofs[t];   // reuse as cursor
    __syncthreads();
    for (int p = s0 + t; p < s1; p += 256) {
        int2 r = tmp[p];
        uint_t x = (uint_t)r.x;
        int ldst = (x >> 25) & 0x7F;
        int idx = atomicAdd(&cnt[ldst], 1);
        int2 o;
        o.x = (int)(x & 0x7FFFFF) | (((int)(x >> 23) & 3) << 20);  // src | et<<20
        o.y = r.y;
        ebuf[s0 + idx] = o;
    }
}

// ---------------- weight pre-transpose to fp32 [f][r*O+o] ----------------
__global__ void k_convw(const void* __restrict__ W1, const void* __restrict__ W2,
                        const int* __restrict__ flag,
                        float* __restrict__ Wf1, float* __restrict__ Wf2) {
    int isb = flag[0];
    int t = threadIdx.x;
    for (int idx = t; idx < 128 * 60; idx += 256) {
        int f = idx / 60, j = idx % 60, r = j / 15, o = j % 15;
        Wf1[idx] = loadf(W1, (r * 128 + f) * 15 + o, isb);
    }
    for (int idx = t; idx < 15 * 40; idx += 256) {
        int f = idx / 40, j = idx % 40, r = j / 10, o = j % 10;
        Wf2[idx] = loadf(W2, (r * 15 + f) * 10 + o, isb);
    }
}

// ---------------- layer-1 transform ----------------
// Block = 256 thr = 4 waves; block covers 64 nodes; wave r computes relation r.
// Node rows staged in LDS (bf16); relation is wave-uniform -> Wf via s_load.
__global__ __launch_bounds__(256) void k_t1(const void* __restrict__ xin,
                                            const float* __restrict__ Wf,
                                            const void* __restrict__ qb,
                                            const void* __restrict__ kb,
                                            const int* __restrict__ flag,
                                            float* __restrict__ xt,
                                            float* __restrict__ dq,
                                            float* __restrict__ dk, int N) {
    __shared__ __align__(16) ushort_t sx[64 * 136];  // row stride 136 (16B-mult, ~2-way banks)
    int isb = flag[0];
    int t = threadIdx.x;
    int lane = t & 63;
    int r = t >> 6;                 // wave id = relation (wave-uniform)
    int n0 = blockIdx.x * 64;
    if (isb) {
        // stage 64 rows x 128 bf16, coalesced uint4 loads
        int j = t >> 4, c = t & 15;
        const uint4* g = (const uint4*)xin;
        for (int it = 0; it < 4; ++it, j += 16) {
            int nn = n0 + j;
            if (nn < N) *(uint4*)(&sx[j * 136 + c * 8]) = g[(size_t)nn * 16 + c];
        }
    }
    __syncthreads();
    int n = n0 + lane;
    if (n >= N) return;
    float acc[15];
#pragma unroll
    for (int o = 0; o < 15; ++o) acc[o] = 0.f;
    if (isb) {
        const ushort_t* row = &sx[lane * 136];
        for (int c = 0; c < 16; ++c) {
            uint4 u = *(const uint4*)(row + c * 8);
            uint_t w[4] = {u.x, u.y, u.z, u.w};
#pragma unroll
            for (int h = 0; h < 4; ++h) {
                float x0 = __uint_as_float(w[h] << 16);
                float x1 = __uint_as_float(w[h] & 0xFFFF0000u);
                const float* wp = Wf + (c * 8 + h * 2) * 60 + r * 15;
#pragma unroll
                for (int o = 0; o < 15; ++o) acc[o] += x0 * wp[o];
#pragma unroll
                for (int o = 0; o < 15; ++o) acc[o] += x1 * wp[60 + o];
            }
        }
    } else {
        const float4* x4 = (const float4*)((const float*)xin + (size_t)n * 128);
        for (int c = 0; c < 32; ++c) {
            float4 u = x4[c];
            const float* wp = Wf + c * 4 * 60 + r * 15;
#pragma unroll
            for (int o = 0; o < 15; ++o) acc[o] += u.x * wp[o];
#pragma unroll
            for (int o = 0; o < 15; ++o) acc[o] += u.y * wp[60 + o];
#pragma unroll
            for (int o = 0; o < 15; ++o) acc[o] += u.z * wp[120 + o];
#pragma unroll
            for (int o = 0; o < 15; ++o) acc[o] += u.w * wp[180 + o];
        }
    }
    float a = 0.f, b = 0.f;
#pragma unroll
    for (int o = 0; o < 15; ++o) {
        a += acc[o] * loadf(qb, o, isb);
        b += acc[o] * loadf(kb, o, isb);
    }
    dq[n * 4 + r] = a;
    dk[n * 4 + r] = b;
    float* xr = xt + (size_t)n * 64 + r * 16;
    *(float4*)(xr + 0)  = make_float4(acc[0], acc[1], acc[2], acc[3]);
    *(float4*)(xr + 4)  = make_float4(acc[4], acc[5], acc[6], acc[7]);
    *(float4*)(xr + 8)  = make_float4(acc[8], acc[9], acc[10], acc[11]);
    *(float4*)(xr + 12) = make_float4(acc[12], acc[13], acc[14], 0.f);
}

// ---------------- layer-2 transform: BN1+ELU fused, wave-per-relation ----------------
__global__ __launch_bounds__(256) void k_t2(const float* __restrict__ in,
                                            const float* __restrict__ stats,
                                            const void* __restrict__ g,
                                            const void* __restrict__ beta,
                                            const float* __restrict__ Wf,
                                            const void* __restrict__ qb,
                                            const void* __restrict__ kb,
                                            const int* __restrict__ flag,
                                            float* __restrict__ xt,
                                            float* __restrict__ dq,
                                            float* __restrict__ dk, int N) {
    int isb = flag[0];
    int t = threadIdx.x;
    int lane = t & 63;
    int r = t >> 6;                 // wave-uniform relation
    int n = blockIdx.x * 64 + lane;
    if (n >= N) return;
    float invN = 1.f / (float)N;
    float v[15];
#pragma unroll
    for (int c = 0; c < 15; ++c) {
        float mean = stats[c] * invN;
        float var = stats[16 + c] * invN - mean * mean;
        float inv = rsqrtf(var + BN_EPS);
        float h = (in[(size_t)n * 15 + c] - mean) * inv * loadf(g, c, isb) + loadf(beta, c, isb);
        v[c] = h > 0.f ? h : expm1f(h);  // ELU
    }
    float acc[10];
#pragma unroll
    for (int o = 0; o < 10; ++o) acc[o] = 0.f;
#pragma unroll
    for (int f = 0; f < 15; ++f) {
        const float* wp = Wf + f * 40 + r * 10;
#pragma unroll
        for (int o = 0; o < 10; ++o) acc[o] += v[f] * wp[o];
    }
    float a = 0.f, b = 0.f;
#pragma unroll
    for (int o = 0; o < 10; ++o) {
        a += acc[o] * loadf(qb, o, isb);
        b += acc[o] * loadf(kb, o, isb);
    }
    dq[n * 4 + r] = a;
    dk[n * 4 + r] = b;
    float* xr = xt + (size_t)n * 64 + r * 16;
    *(float4*)(xr + 0)  = make_float4(acc[0], acc[1], acc[2], acc[3]);
    *(float4*)(xr + 4)  = make_float4(acc[4], acc[5], acc[6], acc[7]);
    *(float4*)(xr + 8)  = make_float4(acc[8], acc[9], 0.f, 0.f);
    *(float4*)(xr + 12) = make_float4(0.f, 0.f, 0.f, 0.f);
}

// ---------------- per-node gather: softmax + weighted aggregation ----------------
template <int O>
__global__ __launch_bounds__(256) void k_gather(const int* __restrict__ row_ptr,
                                                const int2* __restrict__ ebuf,
                                                const float* __restrict__ dq,
                                                const float* __restrict__ dk,
                                                const float* __restrict__ xt,
                                                const void* __restrict__ Web,
                                                const void* __restrict__ eb,
                                                const void* __restrict__ bb,
                                                const int* __restrict__ flag,
                                                float* __restrict__ out, int N) {
    __shared__ float sA[4 * CAP];
    __shared__ int   sP[4 * CAP];
    int isb = flag[0];
    int lane = threadIdx.x & 63;
    int w = threadIdx.x >> 6;
    int n = blockIdx.x * 4 + w;
    if (n >= N) return;
    float c = 0.f;  // scalar (We . e)
#pragma unroll
    for (int o = 0; o < O; ++o) c += loadf(Web, o, isb) * loadf(eb, o, isb);
    int start = row_ptr[n], end = row_ptr[n + 1];
    float dq0 = dq[n * 4], dq1 = dq[n * 4 + 1], dq2 = dq[n * 4 + 2], dq3 = dq[n * 4 + 3];

    // Phase A: online softmax; cache alpha + packed edge in LDS
    float m = -1e30f, s = 0.f;
    for (int p = start + lane; p < end; p += 64) {
        int2 rec = ebuf[p];
        int sr = rec.x & 0xFFFFF, et = rec.x >> 20;
        float dqv = et < 2 ? (et == 0 ? dq0 : dq1) : (et == 2 ? dq2 : dq3);
        float a = dqv + dk[sr * 4 + et] + c * __int_as_float(rec.y);
        a = a > 0.f ? a : NEG_SLOPE * a;
        int idx = p - start;
        if (idx < CAP) { sA[w * CAP + idx] = a; sP[w * CAP + idx] = rec.x; }
        float mn = fmaxf(m, a);
        s = s * __expf(m - mn) + __expf(a - mn);
        m = mn;
    }
#pragma unroll
    for (int off = 32; off; off >>= 1) {
        float m2 = __shfl_xor(m, off, 64);
        float s2 = __shfl_xor(s, off, 64);
        float mn = fmaxf(m, m2);
        s = s * __expf(m - mn) + s2 * __expf(m2 - mn);
        m = mn;
    }
    float inv = 1.f / (s + 1e-16f);

    // Phase B: weighted aggregation, channels across lanes (padded 64B rows)
    int g = lane >> 4, ch = lane & 15;
    float acc = 0.f;
    for (int p = start + g; p < end; p += 4) {
        int idx = p - start;
        int pk; float a;
        if (idx < CAP) {
            pk = sP[w * CAP + idx];
            a = sA[w * CAP + idx];
        } else {
            int2 rec = ebuf[p];
            pk = rec.x;
            int sr = pk & 0xFFFFF, et = pk >> 20;
            float dqv = et < 2 ? (et == 0 ? dq0 : dq1) : (et == 2 ? dq2 : dq3);
            a = dqv + dk[sr * 4 + et] + c * __int_as_float(rec.y);
            a = a > 0.f ? a : NEG_SLOPE * a;
        }
        float coeff = __expf(a - m) * inv;
        int sr = pk & 0xFFFFF, et = pk >> 20;
        acc += coeff * xt[(size_t)(sr * 4 + et) * 16 + ch];
    }
    acc += __shfl_xor(acc, 16, 64);
    acc += __shfl_xor(acc, 32, 64);
    if (lane < O) out[(size_t)n * O + lane] = acc + loadf(bb, lane, isb);
}

// ---------------- BN batch statistics (sum, sumsq per channel) ----------------
template <int C>
__global__ __launch_bounds__(256) void k_bnstats(const float* __restrict__ in,
                                                 float* __restrict__ S, int N) {
    int t = threadIdx.x;
    int ch = t & 15, rg = t >> 4;
    float s1 = 0.f, s2 = 0.f;
    int row0 = blockIdx.x * 256;
    int rowEnd = row0 + 256;
    if (rowEnd > N) rowEnd = N;
    if (ch < C) {
        for (int r = row0 + rg; r < rowEnd; r += 16) {
            float v = in[(size_t)r * C + ch];
            s1 += v;
            s2 += v * v;
        }
    }
    __shared__ float L1[256], L2[256];
    L1[t] = s1; L2[t] = s2;
    __syncthreads();
    for (int k = 128; k >= 16; k >>= 1) {
        if (t < k) { L1[t] += L1[t + k]; L2[t] += L2[t + k]; }
        __syncthreads();
    }
    if (t < C) {
        atomicAdd(&S[t], L1[t]);
        atomicAdd(&S[16 + t], L2[t]);
    }
}

// ---------------- BN2 + ELU + head, bf16-or-fp32 output ----------------
__global__ __launch_bounds__(256) void k_head(const float* __restrict__ in,
                                              const float* __restrict__ stats,
                                              const void* __restrict__ g,
                                              const void* __restrict__ beta,
                                              const void* __restrict__ wh,
                                              const void* __restrict__ bh,
                                              const int* __restrict__ flag,
                                              void* __restrict__ out, int N) {
    int isb = flag[0];
    int n = blockIdx.x * 256 + threadIdx.x;
    if (n >= N) return;
    float invN = 1.f / (float)N;
    float r = loadf(bh, 0, isb);
#pragma unroll
    for (int c = 0; c < 10; ++c) {
        float mean = stats[c] * invN;
        float var = stats[16 + c] * invN - mean * mean;
        float inv = rsqrtf(var + BN_EPS);
        float h = (in[(size_t)n * 10 + c] - mean) * inv * loadf(g, c, isb) + loadf(beta, c, isb);
        float e = h > 0.f ? h : expm1f(h);
        r += e * loadf(wh, c, isb);
    }
    if (isb) ((ushort_t*)out)[n] = f2bf(r);
    else     ((float*)out)[n] = r;
}

extern "C" void kernel_launch(void* const* d_in, const int* in_sizes, int n_in,
                              void* d_out, int out_size, void* d_ws, size_t ws_size,
                              hipStream_t stream) {
    const void* node_emb  = d_in[0];
    const int*  edge_index = (const int*)d_in[1];
    const int*  edge_types = (const int*)d_in[2];
    const void* edge_attr = d_in[3];
    const void* W1  = d_in[4];
    const void* q1  = d_in[5];
    const void* k1  = d_in[6];
    const void* e1  = d_in[7];
    const void* We1 = d_in[8];
    const void* b1  = d_in[9];
    const void* W2  = d_in[10];
    const void* q2  = d_in[11];
    const void* k2  = d_in[12];
    const void* e2  = d_in[13];
    const void* We2 = d_in[14];
    const void* b2  = d_in[15];
    const void* g1  = d_in[16];
    const void* beta1 = d_in[17];
    const void* g2  = d_in[18];
    const void* beta2 = d_in[19];
    const void* w_head = d_in[20];
    const void* b_head = d_in[21];

    int N = in_sizes[0] / 128;
    int E = in_sizes[1] / 2;
    int npb = (N + NBUCK - 1) / NBUCK;         // nodes per bucket (98)
    int nbuck = (N + npb - 1) / npb;           // used buckets (511)

    char* ws = (char*)d_ws;
    size_t off = 0;
    auto alloc = [&](size_t bytes) -> void* {
        void* p = ws + off;
        off = (off + bytes + 255) & ~(size_t)255;
        return p;
    };
    int*   row_ptr = (int*)alloc(((size_t)N + 1) * 4);
    int*   hist    = (int*)alloc((NBUCK) * 4);
    int*   bbase   = (int*)alloc((NBUCK + 1) * 4);
    int*   bcur    = (int*)alloc((NBUCK) * 4);
    int*   dflag   = (int*)alloc(256);
    int2*  ebuf    = (int2*)alloc((size_t)E * 8);
    // xt (padded 64B rows) overlays ebuf_tmp: tmp dead before k_t1 writes xt
    size_t big = (size_t)N * 64 * 4;
    if ((size_t)E * 8 > big) big = (size_t)E * 8;
    float* xt1     = (float*)alloc(big);
    int2*  etmp    = (int2*)xt1;
    float* dq1     = (float*)alloc((size_t)N * 16);
    float* dk1     = (float*)alloc((size_t)N * 16);
    float* out1    = (float*)alloc((size_t)N * 15 * 4);   // out2 overlays
    float* stats1  = (float*)alloc(128);
    float* stats2  = (float*)alloc(128);
    float* Wf1     = (float*)alloc(7680 * 4);
    float* Wf2     = (float*)alloc(600 * 4);
    // overlays (lifetimes disjoint):
    float* xt2  = xt1;
    float* dq2  = dq1;
    float* dk2  = dk1;
    float* out2 = out1;

    hipMemsetAsync(hist, 0, NBUCK * 4, stream);
    hipMemsetAsync(stats1, 0, 128, stream);
    hipMemsetAsync(stats2, 0, 128, stream);

    int NB_N = (N + 255) / 256;
    int NB_T = (N + 63) / 64;     // transform blocks: 64 nodes x 4 relations
    int NB_G = (N + 3) / 4;
    int NB_H = (E + 4095) / 4096;
    int NB_B = (E + 8191) / 8192;

    k_detect<<<1, 256, 0, stream>>>((const uint_t*)node_emb, dflag);
    k_hist<<<NB_H, 256, 0, stream>>>(edge_index, hist, E, npb);
    k_bscan<<<1, NBUCK, 0, stream>>>(hist, bbase, bcur, row_ptr, N, E);
    k_bucket<<<NB_B, 512, 8192 * sizeof(int2), stream>>>(edge_index, edge_types, edge_attr,
                                                         dflag, bcur, etmp, E, npb);
    k_b2csr<<<nbuck, 256, 0, stream>>>(etmp, bbase, row_ptr, ebuf, N, npb);
    k_convw<<<1, 256, 0, stream>>>(W1, W2, dflag, Wf1, Wf2);

    k_t1<<<NB_T, 256, 0, stream>>>(node_emb, Wf1, q1, k1, dflag, xt1, dq1, dk1, N);
    k_gather<15><<<NB_G, 256, 0, stream>>>(row_ptr, ebuf, dq1, dk1, xt1, We1, e1, b1, dflag, out1, N);
    k_bnstats<15><<<NB_N, 256, 0, stream>>>(out1, stats1, N);
    k_t2<<<NB_T, 256, 0, stream>>>(out1, stats1, g1, beta1, Wf2, q2, k2, dflag, xt2, dq2, dk2, N);
    k_gather<10><<<NB_G, 256, 0, stream>>>(row_ptr, ebuf, dq2, dk2, xt2, We2, e2, b2, dflag, out2, N);
    k_bnstats<10><<<NB_N, 256, 0, stream>>>(out2, stats2, N);
    k_head<<<NB_N, 256, 0, stream>>>(out2, stats2, g2, beta2, w_head, b_head, dflag, d_out, N);
}

// Round 6
// 393.889 us; speedup vs baseline: 1.0990x; 1.0990x over previous
//
#include <hip/hip_runtime.h>

// RGAT 2-layer + BN/ELU + head for MI355X (gfx950).
// Float inputs may be bf16 OR fp32 (runtime-detected); ints are int32.
// Internal compute fp32 in workspace. Output stored in detected float width.
//
// CSR build: 512-bucket LDS-staged partition + per-bucket CSR finalize.
// Layer-1 transform: MFMA GEMM [N,128]@[128,80] where B packs
// {xt padded layout (64 cols), dq cols (4), dk cols (4), pad (8)}.

typedef unsigned short ushort_t;
typedef unsigned int uint_t;
typedef __attribute__((ext_vector_type(8))) short bf16x8;   // 8 bf16 = 4 VGPRs
typedef __attribute__((ext_vector_type(4))) float f32x4;

#define NEG_SLOPE 0.2f
#define BN_EPS 1e-5f
#define CAP 256     // per-node LDS alpha cache in gather (recompute fallback)
#define NBUCK 512   // partition buckets

__device__ __forceinline__ float bf2f(ushort_t u) {
    return __uint_as_float(((uint_t)u) << 16);
}
__device__ __forceinline__ ushort_t f2bf(float f) {
    uint_t x = __float_as_uint(f);
    x += 0x7FFFu + ((x >> 16) & 1u);   // round-to-nearest-even
    return (ushort_t)(x >> 16);
}
// generic float load: bf16 (isb=1) or fp32 (isb=0)
__device__ __forceinline__ float loadf(const void* p, int i, int isb) {
    return isb ? bf2f(((const ushort_t*)p)[i]) : ((const float*)p)[i];
}

// ---------------- input dtype detection ----------------
__global__ void k_detect(const uint_t* __restrict__ x, int* __restrict__ flag) {
    int t = threadIdx.x;
    uint_t u = x[t * 37];
    uint_t lo_exp = (u >> 7) & 0xFF;
    int like = (lo_exp >= 96 && lo_exp <= 150) ? 1 : 0;
    __shared__ int cnt;
    if (t == 0) cnt = 0;
    __syncthreads();
    atomicAdd(&cnt, like);
    __syncthreads();
    if (t == 0) flag[0] = (cnt > 192) ? 1 : 0;
}

// ---------------- bucket histogram ----------------
__global__ __launch_bounds__(256) void k_hist(const int* __restrict__ ei,
                                              int* __restrict__ hist, int E, int npb) {
    __shared__ int h[NBUCK];
    int t = threadIdx.x;
    for (int i = t; i < NBUCK; i += 256) h[i] = 0;
    __syncthreads();
    int e0 = blockIdx.x * 4096;
    for (int i = 0; i < 16; ++i) {
        int e = e0 + i * 256 + t;
        if (e < E) atomicAdd(&h[ei[E + e] / npb], 1);
    }
    __syncthreads();
    for (int i = t; i < NBUCK; i += 256) {
        int c = h[i];
        if (c) atomicAdd(&hist[i], c);
    }
}

// ---------------- bucket base scan ----------------
__global__ __launch_bounds__(NBUCK) void k_bscan(const int* __restrict__ hist,
                                                 int* __restrict__ base,
                                                 int* __restrict__ cursor,
                                                 int* __restrict__ row_ptr,
                                                 int N, int E) {
    __shared__ int sc[NBUCK];
    int t = threadIdx.x;
    int v = hist[t];
    sc[t] = v;
    __syncthreads();
    for (int off = 1; off < NBUCK; off <<= 1) {
        int x = (t >= off) ? sc[t - off] : 0;
        __syncthreads();
        sc[t] += x;
        __syncthreads();
    }
    int ex = sc[t] - v;
    base[t] = ex;
    cursor[t] = ex;
    if (t == NBUCK - 1) { base[NBUCK] = E; row_ptr[N] = E; }
}

// ---------------- LDS-staged bucket partition ----------------
// tmp record: x = src | et<<23 | ldst<<25 ; y = eattr fp32 bits
__global__ __launch_bounds__(512) void k_bucket(const int* __restrict__ ei,
                                                const int* __restrict__ et,
                                                const void* __restrict__ ea,
                                                const int* __restrict__ flag,
                                                int* __restrict__ bcur,
                                                int2* __restrict__ tmp,
                                                int E, int npb) {
    extern __shared__ int2 srec[];           // 8192 records = 64 KB
    __shared__ int cnt[NBUCK];
    __shared__ int lofs[NBUCK + 1];
    __shared__ int gpos[NBUCK];
    int t = threadIdx.x;
    int isb = flag[0];
    cnt[t] = 0;
    __syncthreads();
    int e0 = blockIdx.x * 8192;
    for (int i = 0; i < 16; ++i) {
        int e = e0 + i * 512 + t;
        if (e < E) atomicAdd(&cnt[ei[E + e] / npb], 1);
    }
    __syncthreads();
    int myc = cnt[t];
    for (int off = 1; off < NBUCK; off <<= 1) {
        int v = (t >= off) ? cnt[t - off] : 0;
        __syncthreads();
        cnt[t] += v;
        __syncthreads();
    }
    lofs[t] = cnt[t] - myc;
    if (t == NBUCK - 1) lofs[NBUCK] = cnt[NBUCK - 1];
    __syncthreads();
    cnt[t] = lofs[t];   // reuse as local cursor
    __syncthreads();
    for (int i = 0; i < 16; ++i) {
        int e = e0 + i * 512 + t;
        if (e < E) {
            int d = ei[E + e];
            int b = d / npb;
            int ldst = d - b * npb;
            int idx = atomicAdd(&cnt[b], 1);
            int2 r;
            r.x = (int)((uint_t)ei[e] | ((uint_t)et[e] << 23) | ((uint_t)ldst << 25));
            r.y = __float_as_int(loadf(ea, e, isb));
            srec[idx] = r;
        }
    }
    __syncthreads();
    int c_b = lofs[t + 1] - lofs[t];
    gpos[t] = atomicAdd(&bcur[t], c_b);
    __syncthreads();
    int total = lofs[NBUCK];
    for (int i = t; i < total; i += 512) {
        int lo = 0, hi = NBUCK - 1;
        while (lo < hi) {
            int mid = (lo + hi + 1) >> 1;
            if (lofs[mid] <= i) lo = mid; else hi = mid - 1;
        }
        tmp[gpos[lo] + (i - lofs[lo])] = srec[i];
    }
}

// ---------------- per-bucket CSR finalize ----------------
__global__ __launch_bounds__(256) void k_b2csr(const int2* __restrict__ tmp,
                                               const int* __restrict__ base,
                                               int* __restrict__ row_ptr,
                                               int2* __restrict__ ebuf,
                                               int N, int npb) {
    __shared__ int cnt[128];
    __shared__ int lofs[129];
    int b = blockIdx.x, t = threadIdx.x;
    int s0 = base[b], s1 = base[b + 1];
    if (t < 128) cnt[t] = 0;
    __syncthreads();
    for (int p = s0 + t; p < s1; p += 256) {
        uint_t x = (uint_t)tmp[p].x;
        atomicAdd(&cnt[(x >> 25) & 0x7F], 1);
    }
    __syncthreads();
    int myc = (t < 128) ? cnt[t] : 0;
    for (int off = 1; off < 128; off <<= 1) {
        int v = (t >= off && t < 128) ? cnt[t - off] : 0;
        __syncthreads();
        if (t < 128) cnt[t] += v;
        __syncthreads();
    }
    if (t < 128) {
        lofs[t] = cnt[t] - myc;
        if (t == 127) lofs[128] = cnt[127];
    }
    __syncthreads();
    int node0 = b * npb;
    if (t < npb && node0 + t < N) row_ptr[node0 + t] = s0 + lofs[t];
    if (t < 128) cnt[t] = lofs[t];   // reuse as cursor
    __syncthreads();
    for (int p = s0 + t; p < s1; p += 256) {
        int2 r = tmp[p];
        uint_t x = (uint_t)r.x;
        int ldst = (x >> 25) & 0x7F;
        int idx = atomicAdd(&cnt[ldst], 1);
        int2 o;
        o.x = (int)(x & 0x7FFFFF) | (((int)(x >> 23) & 3) << 20);  // src | et<<20
        o.y = r.y;
        ebuf[s0 + idx] = o;
    }
}

// ---------------- weight prep ----------------
// Wsw: B-matrix [128 x 80] bf16, pre-swizzled into MFMA B-fragment order:
//   col c<64: r=c>>4,o=c&15 -> W1[r][f][o] (o==15 -> 0)
//   c in [64,68): dq col r=c-64: sum_o W1[r][f][o]*q1[o]
//   c in [68,72): dk col r=c-68
//   c >= 72: 0
// frag (ks,ct): lane l, j -> Wbig[ks*32+(l>>4)*8+j][ct*16+(l&15)]
// stored at Wsw[((ks*5+ct)*64 + l)*8 + j]
__global__ __launch_bounds__(256) void k_convw(const void* __restrict__ W1,
                                               const void* __restrict__ W2,
                                               const void* __restrict__ q1b,
                                               const void* __restrict__ k1b,
                                               const int* __restrict__ flag,
                                               ushort_t* __restrict__ Wsw,
                                               float* __restrict__ Wf2) {
    int isb = flag[0];
    int t = threadIdx.x;
    __shared__ float wb[128 * 80];
    for (int idx = t; idx < 128 * 80; idx += 256) {
        int f = idx / 80, c = idx % 80;
        float v = 0.f;
        if (c < 64) {
            int r = c >> 4, o = c & 15;
            if (o < 15) v = loadf(W1, (r * 128 + f) * 15 + o, isb);
        } else if (c < 72) {
            int r = (c - 64) & 3;
            const void* vec = (c < 68) ? q1b : k1b;
            float s = 0.f;
            for (int o = 0; o < 15; ++o)
                s += loadf(W1, (r * 128 + f) * 15 + o, isb) * loadf(vec, o, isb);
            v = s;
        }
        wb[idx] = v;
    }
    __syncthreads();
    for (int idx = t; idx < 20 * 64 * 8; idx += 256) {
        int j = idx & 7, lane = (idx >> 3) & 63, fr = idx >> 9;
        int ks = fr / 5, ct = fr % 5;
        int k = ks * 32 + (lane >> 4) * 8 + j, c = ct * 16 + (lane & 15);
        Wsw[idx] = f2bf(wb[k * 80 + c]);
    }
    for (int idx = t; idx < 15 * 40; idx += 256) {
        int f = idx / 40, j = idx % 40, r = j / 10, o = j % 10;
        Wf2[idx] = loadf(W2, (r * 15 + f) * 10 + o, isb);
    }
}

// ---------------- layer-1 transform: MFMA GEMM ----------------
// One wave per 16-node tile (grid-stride). 20 B-frags held in registers.
// Per tile: 4 A-frag uint4 loads, 20 MFMAs, epilogue stores xt/dq/dk.
__global__ __launch_bounds__(256) void k_t1(const void* __restrict__ xin,
                                            const ushort_t* __restrict__ Wsw,
                                            const int* __restrict__ flag,
                                            float* __restrict__ xt,
                                            float* __restrict__ dq,
                                            float* __restrict__ dk,
                                            int N, int ntiles, int nwaves) {
    int isb = flag[0];
    int lane = threadIdx.x & 63;
    int gw = blockIdx.x * 4 + (threadIdx.x >> 6);
    bf16x8 bfr[20];
    const uint4* wq = (const uint4*)Wsw;
#pragma unroll
    for (int fr = 0; fr < 20; ++fr)
        bfr[fr] = __builtin_bit_cast(bf16x8, wq[fr * 64 + lane]);
    int row = lane & 15, quad = lane >> 4;
    for (int tile = gw; tile < ntiles; tile += nwaves) {
        int n0 = tile * 16;
        f32x4 acc[5];
#pragma unroll
        for (int ct = 0; ct < 5; ++ct) acc[ct] = (f32x4){0.f, 0.f, 0.f, 0.f};
        int nA = n0 + row;
        if (nA >= N) nA = N - 1;
#pragma unroll
        for (int ks = 0; ks < 4; ++ks) {
            bf16x8 af;
            if (isb) {
                uint4 u = *(const uint4*)((const ushort_t*)xin + (size_t)nA * 128 + ks * 32 + quad * 8);
                af = __builtin_bit_cast(bf16x8, u);
            } else {
                const float* xf = (const float*)xin + (size_t)nA * 128 + ks * 32 + quad * 8;
#pragma unroll
                for (int j = 0; j < 8; ++j) af[j] = (short)f2bf(xf[j]);
            }
#pragma unroll
            for (int ct = 0; ct < 5; ++ct)
                acc[ct] = __builtin_amdgcn_mfma_f32_16x16x32_bf16(af, bfr[ks * 5 + ct], acc[ct], 0, 0, 0);
        }
#pragma unroll
        for (int i = 0; i < 4; ++i) {
            int n = n0 + quad * 4 + i;
            if (n < N) {
#pragma unroll
                for (int ct = 0; ct < 4; ++ct)
                    xt[(size_t)n * 64 + ct * 16 + row] = acc[ct][i];
                if (row < 4) dq[n * 4 + row] = acc[4][i];
                else if (row < 8) dk[n * 4 + (row - 4)] = acc[4][i];
            }
        }
    }
}

// ---------------- layer-2 transform: BN1+ELU fused, wave-per-relation ----------------
__global__ __launch_bounds__(256) void k_t2(const float* __restrict__ in,
                                            const float* __restrict__ stats,
                                            const void* __restrict__ g,
                                            const void* __restrict__ beta,
                                            const float* __restrict__ Wf,
                                            const void* __restrict__ qb,
                                            const void* __restrict__ kb,
                                            const int* __restrict__ flag,
                                            float* __restrict__ xt,
                                            float* __restrict__ dq,
                                            float* __restrict__ dk, int N) {
    int isb = flag[0];
    int t = threadIdx.x;
    int lane = t & 63;
    int r = t >> 6;                 // wave-uniform relation
    int n = blockIdx.x * 64 + lane;
    if (n >= N) return;
    float invN = 1.f / (float)N;
    float v[15];
#pragma unroll
    for (int c = 0; c < 15; ++c) {
        float mean = stats[c] * invN;
        float var = stats[16 + c] * invN - mean * mean;
        float inv = rsqrtf(var + BN_EPS);
        float h = (in[(size_t)n * 15 + c] - mean) * inv * loadf(g, c, isb) + loadf(beta, c, isb);
        v[c] = h > 0.f ? h : expm1f(h);  // ELU
    }
    float acc[10];
#pragma unroll
    for (int o = 0; o < 10; ++o) acc[o] = 0.f;
#pragma unroll
    for (int f = 0; f < 15; ++f) {
        const float* wp = Wf + f * 40 + r * 10;
#pragma unroll
        for (int o = 0; o < 10; ++o) acc[o] += v[f] * wp[o];
    }
    float a = 0.f, b = 0.f;
#pragma unroll
    for (int o = 0; o < 10; ++o) {
        a += acc[o] * loadf(qb, o, isb);
        b += acc[o] * loadf(kb, o, isb);
    }
    dq[n * 4 + r] = a;
    dk[n * 4 + r] = b;
    float* xr = xt + (size_t)n * 64 + r * 16;
    *(float4*)(xr + 0)  = make_float4(acc[0], acc[1], acc[2], acc[3]);
    *(float4*)(xr + 4)  = make_float4(acc[4], acc[5], acc[6], acc[7]);
    *(float4*)(xr + 8)  = make_float4(acc[8], acc[9], 0.f, 0.f);
    *(float4*)(xr + 12) = make_float4(0.f, 0.f, 0.f, 0.f);
}

// ---------------- per-node gather: softmax + weighted aggregation ----------------
template <int O>
__global__ __launch_bounds__(256) void k_gather(const int* __restrict__ row_ptr,
                                                const int2* __restrict__ ebuf,
                                                const float* __restrict__ dq,
                                                const float* __restrict__ dk,
                                                const float* __restrict__ xt,
                                                const void* __restrict__ Web,
                                                const void* __restrict__ eb,
                                                const void* __restrict__ bb,
                                                const int* __restrict__ flag,
                                                float* __restrict__ out, int N) {
    __shared__ float sA[4 * CAP];
    __shared__ int   sP[4 * CAP];
    int isb = flag[0];
    int lane = threadIdx.x & 63;
    int w = threadIdx.x >> 6;
    int n = blockIdx.x * 4 + w;
    if (n >= N) return;
    float c = 0.f;  // scalar (We . e)
#pragma unroll
    for (int o = 0; o < O; ++o) c += loadf(Web, o, isb) * loadf(eb, o, isb);
    int start = row_ptr[n], end = row_ptr[n + 1];
    float dq0 = dq[n * 4], dq1 = dq[n * 4 + 1], dq2 = dq[n * 4 + 2], dq3 = dq[n * 4 + 3];

    float m = -1e30f, s = 0.f;
    for (int p = start + lane; p < end; p += 64) {
        int2 rec = ebuf[p];
        int sr = rec.x & 0xFFFFF, et = rec.x >> 20;
        float dqv = et < 2 ? (et == 0 ? dq0 : dq1) : (et == 2 ? dq2 : dq3);
        float a = dqv + dk[sr * 4 + et] + c * __int_as_float(rec.y);
        a = a > 0.f ? a : NEG_SLOPE * a;
        int idx = p - start;
        if (idx < CAP) { sA[w * CAP + idx] = a; sP[w * CAP + idx] = rec.x; }
        float mn = fmaxf(m, a);
        s = s * __expf(m - mn) + __expf(a - mn);
        m = mn;
    }
#pragma unroll
    for (int off = 32; off; off >>= 1) {
        float m2 = __shfl_xor(m, off, 64);
        float s2 = __shfl_xor(s, off, 64);
        float mn = fmaxf(m, m2);
        s = s * __expf(m - mn) + s2 * __expf(m2 - mn);
        m = mn;
    }
    float inv = 1.f / (s + 1e-16f);

    int g = lane >> 4, ch = lane & 15;
    float acc = 0.f;
    for (int p = start + g; p < end; p += 4) {
        int idx = p - start;
        int pk; float a;
        if (idx < CAP) {
            pk = sP[w * CAP + idx];
            a = sA[w * CAP + idx];
        } else {
            int2 rec = ebuf[p];
            pk = rec.x;
            int sr = pk & 0xFFFFF, et = pk >> 20;
            float dqv = et < 2 ? (et == 0 ? dq0 : dq1) : (et == 2 ? dq2 : dq3);
            a = dqv + dk[sr * 4 + et] + c * __int_as_float(rec.y);
            a = a > 0.f ? a : NEG_SLOPE * a;
        }
        float coeff = __expf(a - m) * inv;
        int sr = pk & 0xFFFFF, et = pk >> 20;
        acc += coeff * xt[(size_t)(sr * 4 + et) * 16 + ch];
    }
    acc += __shfl_xor(acc, 16, 64);
    acc += __shfl_xor(acc, 32, 64);
    if (lane < O) out[(size_t)n * O + lane] = acc + loadf(bb, lane, isb);
}

// ---------------- BN batch statistics (sum, sumsq per channel) ----------------
template <int C>
__global__ __launch_bounds__(256) void k_bnstats(const float* __restrict__ in,
                                                 float* __restrict__ S, int N) {
    int t = threadIdx.x;
    int ch = t & 15, rg = t >> 4;
    float s1 = 0.f, s2 = 0.f;
    int row0 = blockIdx.x * 256;
    int rowEnd = row0 + 256;
    if (rowEnd > N) rowEnd = N;
    if (ch < C) {
        for (int r = row0 + rg; r < rowEnd; r += 16) {
            float v = in[(size_t)r * C + ch];
            s1 += v;
            s2 += v * v;
        }
    }
    __shared__ float L1[256], L2[256];
    L1[t] = s1; L2[t] = s2;
    __syncthreads();
    for (int k = 128; k >= 16; k >>= 1) {
        if (t < k) { L1[t] += L1[t + k]; L2[t] += L2[t + k]; }
        __syncthreads();
    }
    if (t < C) {
        atomicAdd(&S[t], L1[t]);
        atomicAdd(&S[16 + t], L2[t]);
    }
}

// ---------------- BN2 + ELU + head, bf16-or-fp32 output ----------------
__global__ __launch_bounds__(256) void k_head(const float* __restrict__ in,
                                              const float* __restrict__ stats,
                                              const void* __restrict__ g,
                                              const void* __restrict__ beta,
                                              const void* __restrict__ wh,
                                              const void* __restrict__ bh,
                                              const int* __restrict__ flag,
                                              void* __restrict__ out, int N) {
    int isb = flag[0];
    int n = blockIdx.x * 256 + threadIdx.x;
    if (n >= N) return;
    float invN = 1.f / (float)N;
    float r = loadf(bh, 0, isb);
#pragma unroll
    for (int c = 0; c < 10; ++c) {
        float mean = stats[c] * invN;
        float var = stats[16 + c] * invN - mean * mean;
        float inv = rsqrtf(var + BN_EPS);
        float h = (in[(size_t)n * 10 + c] - mean) * inv * loadf(g, c, isb) + loadf(beta, c, isb);
        float e = h > 0.f ? h : expm1f(h);
        r += e * loadf(wh, c, isb);
    }
    if (isb) ((ushort_t*)out)[n] = f2bf(r);
    else     ((float*)out)[n] = r;
}

extern "C" void kernel_launch(void* const* d_in, const int* in_sizes, int n_in,
                              void* d_out, int out_size, void* d_ws, size_t ws_size,
                              hipStream_t stream) {
    const void* node_emb  = d_in[0];
    const int*  edge_index = (const int*)d_in[1];
    const int*  edge_types = (const int*)d_in[2];
    const void* edge_attr = d_in[3];
    const void* W1  = d_in[4];
    const void* q1  = d_in[5];
    const void* k1  = d_in[6];
    const void* e1  = d_in[7];
    const void* We1 = d_in[8];
    const void* b1  = d_in[9];
    const void* W2  = d_in[10];
    const void* q2  = d_in[11];
    const void* k2  = d_in[12];
    const void* e2  = d_in[13];
    const void* We2 = d_in[14];
    const void* b2  = d_in[15];
    const void* g1  = d_in[16];
    const void* beta1 = d_in[17];
    const void* g2  = d_in[18];
    const void* beta2 = d_in[19];
    const void* w_head = d_in[20];
    const void* b_head = d_in[21];

    int N = in_sizes[0] / 128;
    int E = in_sizes[1] / 2;
    int npb = (N + NBUCK - 1) / NBUCK;         // nodes per bucket (98)
    int nbuck = (N + npb - 1) / npb;           // used buckets (511)

    char* ws = (char*)d_ws;
    size_t off = 0;
    auto alloc = [&](size_t bytes) -> void* {
        void* p = ws + off;
        off = (off + bytes + 255) & ~(size_t)255;
        return p;
    };
    int*   row_ptr = (int*)alloc(((size_t)N + 1) * 4);
    int*   hist    = (int*)alloc((NBUCK) * 4);
    int*   bbase   = (int*)alloc((NBUCK + 1) * 4);
    int*   bcur    = (int*)alloc((NBUCK) * 4);
    int*   dflag   = (int*)alloc(256);
    int2*  ebuf    = (int2*)alloc((size_t)E * 8);
    // xt (padded 64B rows) overlays ebuf_tmp: tmp dead before k_t1 writes xt
    size_t big = (size_t)N * 64 * 4;
    if ((size_t)E * 8 > big) big = (size_t)E * 8;
    float* xt1     = (float*)alloc(big);
    int2*  etmp    = (int2*)xt1;
    float* dq1     = (float*)alloc((size_t)N * 16);
    float* dk1     = (float*)alloc((size_t)N * 16);
    float* out1    = (float*)alloc((size_t)N * 15 * 4);   // out2 overlays
    float* stats1  = (float*)alloc(128);
    float* stats2  = (float*)alloc(128);
    ushort_t* Wsw  = (ushort_t*)alloc(20 * 64 * 8 * 2);   // 20 KB B-frags
    float* Wf2     = (float*)alloc(600 * 4);
    // overlays (lifetimes disjoint):
    float* xt2  = xt1;
    float* dq2  = dq1;
    float* dk2  = dk1;
    float* out2 = out1;

    hipMemsetAsync(hist, 0, NBUCK * 4, stream);
    hipMemsetAsync(stats1, 0, 128, stream);
    hipMemsetAsync(stats2, 0, 128, stream);

    int NB_N = (N + 255) / 256;
    int NB_T2 = (N + 63) / 64;    // k_t2 blocks: 64 nodes x 4 relations
    int NB_G = (N + 3) / 4;
    int NB_H = (E + 4095) / 4096;
    int NB_B = (E + 8191) / 8192;
    int ntiles = (N + 15) / 16;   // 3125
    int NB_T1 = 391;              // grid-stride waves = 391*4 = 1564
    int nwaves = NB_T1 * 4;

    k_detect<<<1, 256, 0, stream>>>((const uint_t*)node_emb, dflag);
    k_hist<<<NB_H, 256, 0, stream>>>(edge_index, hist, E, npb);
    k_bscan<<<1, NBUCK, 0, stream>>>(hist, bbase, bcur, row_ptr, N, E);
    k_bucket<<<NB_B, 512, 8192 * sizeof(int2), stream>>>(edge_index, edge_types, edge_attr,
                                                         dflag, bcur, etmp, E, npb);
    k_b2csr<<<nbuck, 256, 0, stream>>>(etmp, bbase, row_ptr, ebuf, N, npb);
    k_convw<<<1, 256, 0, stream>>>(W1, W2, q1, k1, dflag, Wsw, Wf2);

    k_t1<<<NB_T1, 256, 0, stream>>>(node_emb, Wsw, dflag, xt1, dq1, dk1, N, ntiles, nwaves);
    k_gather<15><<<NB_G, 256, 0, stream>>>(row_ptr, ebuf, dq1, dk1, xt1, We1, e1, b1, dflag, out1, N);
    k_bnstats<15><<<NB_N, 256, 0, stream>>>(out1, stats1, N);
    k_t2<<<NB_T2, 256, 0, stream>>>(out1, stats1, g1, beta1, Wf2, q2, k2, dflag, xt2, dq2, dk2, N);
    k_gather<10><<<NB_G, 256, 0, stream>>>(row_ptr, ebuf, dq2, dk2, xt2, We2, e2, b2, dflag, out2, N);
    k_bnstats<10><<<NB_N, 256, 0, stream>>>(out2, stats2, N);
    k_head<<<NB_N, 256, 0, stream>>>(out2, stats2, g2, beta2, w_head, b_head, dflag, d_out, N);
}